// Round 6
// baseline (449.003 us; speedup 1.0000x reference)
//
#include <hip/hip_runtime.h>

#define NN 8192
#define SBS 512
#define NSB 16
#define LOG2E 1.44269504088896f

// ws ints: [0]=F_SUBDONE (monotone k*8+m+1); FR(k,w) per-(k,target) lines
#define FR(k,w) (32 + ((k)*8 + (w))*32)
// ws floats: partials [8192,16384) | cp[9][NN] [16384,90112) | s_arr [90112,98304)
#define PART_OFF 8192
#define CP_OFF   16384
#define NCPROW   9
#define SARR_OFF (CP_OFF + NCPROW * NN)

__device__ __forceinline__ float bcastf(float v, int lane) {
    return __int_as_float(__builtin_amdgcn_readlane(__float_as_int(v), lane));
}
__device__ __forceinline__ float sigm(float prelog) {   // pre already in log2e units
    return __builtin_amdgcn_rcpf(1.0f + __builtin_amdgcn_exp2f(-prelog));
}
__device__ __forceinline__ int ld_flag(const int* p) {
    return __hip_atomic_load(p, __ATOMIC_RELAXED, __HIP_MEMORY_SCOPE_AGENT);
}
__device__ __forceinline__ void st_rel(int* p, int v) {
    __hip_atomic_store(p, v, __ATOMIC_RELEASE, __HIP_MEMORY_SCOPE_AGENT);
}
__device__ __forceinline__ float ldf(const float* p) {
    return __hip_atomic_load(p, __ATOMIC_RELAXED, __HIP_MEMORY_SCOPE_AGENT);
}
__device__ __forceinline__ void stf(float* p, float v) {
    __hip_atomic_store(p, v, __ATOMIC_RELAXED, __HIP_MEMORY_SCOPE_AGENT);
}
// barrier that does NOT drain vmcnt (keeps streamed prefetch loads in flight)
#define LBAR() do { asm volatile("s_waitcnt lgkmcnt(0)\ns_barrier" ::: "memory"); \
                    __builtin_amdgcn_sched_barrier(0); } while (0)

__global__ void init_ws(int* wsi, float* wsf) {
    int i = blockIdx.x * 256 + threadIdx.x;   // grid 288*256 = 73728 = 9*NN
    if (i < 8192) wsi[i] = 0;
    wsf[CP_OFF + i] = 0.0f;
}

// ---------- solver WG (bid 0): 8 waves; wave w owns cols [k*512 + w*64, +64) ----------
__device__ void solver_fn(const float* __restrict__ W, const float* __restrict__ b,
                          const float* __restrict__ x, float* wsf, int* flags,
                          float* sdiag, float* spub, float* sacc,
                          float (*redN)[8][64], float* __restrict__ out, int k) {
    const int tid = threadIdx.x;
    const int w = tid >> 6, l = tid & 63;
    const int dj = tid >> 3, dc = (tid & 7) * 8;   // diag staging role
    const int J0 = k * SBS;
    const float* cp = wsf + CP_OFF;
    float* partials = wsf + PART_OFF;
    float* s_arr = wsf + SARR_OFF;

    auto load_diag = [&](int mm, float4& a, float4& bq) {
        if (dj < dc + 7) {   // skip chunks entirely at/below the diagonal (written as 0)
            const float* p = &W[(size_t)(J0 + mm*64 + dj) * NN + (J0 + mm*64 + dc)];
            a  = *(const float4*)p;
            bq = *(const float4*)(p + 4);
        } else {
            a = make_float4(0.f,0.f,0.f,0.f); bq = make_float4(0.f,0.f,0.f,0.f);
        }
    };
    auto write_diag = [&](int mm, float4 a, float4 bq) {
        float* dst = &sdiag[mm*4096 + dj*64 + dc];
        float v[8] = {a.x, a.y, a.z, a.w, bq.x, bq.y, bq.z, bq.w};
        #pragma unroll
        for (int e = 0; e < 8; ++e) dst[e] = (dj < dc + e) ? v[e] * LOG2E : 0.0f;
    };
    auto load_pan1 = [&](int mm, float* pr) {   // source mm -> target mm+1
        #pragma unroll
        for (int r = 0; r < 8; ++r)
            pr[r] = W[(size_t)(J0 + mm*64 + w*8 + r) * NN + (J0 + (mm+1)*64 + l)];
    };

    // ---- prologue: need-ordered issue ----
    const float x0 = x[0], x1 = x[1];
    float base = b[J0 + tid];
    #pragma unroll
    for (int r = 0; r < NCPROW; ++r) base += cp[r * NN + J0 + tid];
    float4 dA[2], dB[2];
    load_diag(0, dA[0], dB[0]);
    load_diag(1, dA[1], dB[1]);
    float p1[2][8];
    load_pan1(0, p1[0]);
    load_pan1(1, p1[1]);
    write_diag(0, dA[0], dB[0]);
    write_diag(1, dA[1], dB[1]);
    sacc[tid] = base;
    LBAR();

    #pragma unroll
    for (int m = 0; m < 8; ++m) {
        if (w == m) {
            float part = 0.0f;
            if (m >= 2) {                       // helper contribution (distance >= 2)
                const int* fl = &flags[FR(k, m)];
                while (ld_flag(fl) == 0) {}
                __builtin_amdgcn_fence(__ATOMIC_ACQUIRE, "agent");
                part = ldf(&partials[((size_t)k*8 + m)*64 + l]);
            }
            float rsum = 0.0f;
            if (m >= 1) {
                #pragma unroll
                for (int g = 0; g < 8; ++g) rsum += redN[m & 1][g][l];
            }
            float acc = (sacc[m*64 + l] + rsum + part) * LOG2E;
            float smine = 0.0f;
            const bool first = (k == 0) && (m == 0);
            #pragma unroll
            for (int j = 0; j < 64; ++j) {
                const float pre = bcastf(acc, j);
                float s;
                if (first && j == 0)      s = x0;
                else if (first && j == 1) s = x1;
                else                      s = sigm(pre);
                acc += sdiag[m*4096 + j*64 + l] * s;   // 0 for j>=l
                if (l == j) smine = s;
            }
            spub[m*64 + l] = smine;
            stf(&s_arr[J0 + m*64 + l], smine);
            if (k == NSB - 1 && m == 7 && l == 63) out[0] = smine;
            if (l == 0) st_rel(&flags[0], k*8 + m + 1);
        }
        LBAR();                                   // spub visible to folds
        if (m < 7) {
            // local distance-1 fold: source m -> target m+1
            float f1 = 0.0f;
            #pragma unroll
            for (int r = 0; r < 8; ++r)
                f1 += p1[m & 1][r] * spub[m*64 + w*8 + r];
            redN[(m+1) & 1][w][l] = f1;
            // staging pipeline (2-window)
            if (m >= 1) write_diag(m + 1, dA[(m+1) & 1], dB[(m+1) & 1]);
            if (m + 2 <= 7) load_diag(m + 2, dA[(m+2) & 1], dB[(m+2) & 1]);
            if (m + 2 <= 6) load_pan1(m + 2, p1[m & 1]);
            LBAR();                               // red + diag writes visible
        }
    }
}

// ---------- helper WG (bids 8..48, solver's XCD): target TW, folds sources 0..TW-2 ----------
template <int TW>
__device__ void helper_fn(const float* __restrict__ W, float* wsf, int* flags,
                          float (*redh)[64], int k) {
    const int tid = threadIdx.x, g = tid >> 6, l = tid & 63;
    float* partials = wsf + PART_OFF;
    const float* s_arr = wsf + SARR_OFF;
    const int J0 = k * SBS;

    float pr[TW - 1][8];
    #pragma unroll
    for (int m = 0; m <= TW - 2; ++m)
        #pragma unroll
        for (int r = 0; r < 8; ++r)
            pr[m][r] = W[(size_t)(J0 + m*64 + g*8 + r) * NN + (J0 + TW*64 + l)];

    float part = 0.0f;
    #pragma unroll
    for (int m = 0; m <= TW - 2; ++m) {
        if (tid < 64) {
            while (ld_flag(&flags[0]) < k*8 + m + 1) __builtin_amdgcn_s_sleep(1);
        }
        __syncthreads();
        __builtin_amdgcn_fence(__ATOMIC_ACQUIRE, "agent");
        #pragma unroll
        for (int r = 0; r < 8; ++r)
            part += pr[m][r] * ldf(&s_arr[J0 + m*64 + g*8 + r]);
    }
    redh[g][l] = part;
    __syncthreads();
    if (tid < 64) {
        float tot = 0.0f;
        #pragma unroll
        for (int g2 = 0; g2 < 8; ++g2) tot += redh[g2][tid];
        stf(&partials[((size_t)k*8 + TW)*64 + tid], tot);
    }
    __syncthreads();
    if (tid == 0) st_rel(&flags[FR(k, TW)], 1);
}

// ---------- prefetch WG (bid 56, solver's XCD): warm L2/L3 with block k+1's solver reads ----------
__device__ void prefetch_fn(const float* __restrict__ W, int k) {
    const int tid = threadIdx.x;
    const int w = tid >> 6, l = tid & 63;
    const int dj = tid >> 3, dc = (tid & 7) * 8;
    const int J0 = (k + 1) * SBS;
    float s = 0.0f;
    #pragma unroll
    for (int mm = 0; mm < 8; ++mm) {
        if (dj < dc + 7) {
            const float* p = &W[(size_t)(J0 + mm*64 + dj) * NN + (J0 + mm*64 + dc)];
            float4 a = *(const float4*)p, bq = *(const float4*)(p + 4);
            s += (a.x + a.y) + (a.z + a.w) + (bq.x + bq.y) + (bq.z + bq.w);
        }
    }
    #pragma unroll
    for (int mm = 0; mm < 7; ++mm)
        #pragma unroll
        for (int r = 0; r < 8; ++r)
            s += W[(size_t)(J0 + mm*64 + w*8 + r) * NN + (J0 + (mm+1)*64 + l)];
    asm volatile("" :: "v"(s));   // keep loads live; no stores
}

// ---------- near WG: block k -> block k+1, target sub-block t (progressive) ----------
__device__ void near_fn(const float* __restrict__ W, float* wsf, int* flags,
                        float (*redh)[64], int t, int k) {
    const int tid = threadIdx.x, g = tid >> 6, l = tid & 63;
    const int col = (k+1)*SBS + t*64 + l;
    const float* s_arr = wsf + SARR_OFF;
    float* cp = wsf + CP_OFF;

    float pr[8][8];
    #pragma unroll
    for (int m = 0; m < 8; ++m)
        #pragma unroll
        for (int r = 0; r < 8; ++r)
            pr[m][r] = W[(size_t)(k*SBS + m*64 + g*8 + r) * NN + col];

    float part = 0.0f;
    #pragma unroll
    for (int m = 0; m < 8; ++m) {
        if (tid < 64) {
            while (ld_flag(&flags[0]) < k*8 + m + 1) __builtin_amdgcn_s_sleep(4);
        }
        __syncthreads();
        __builtin_amdgcn_fence(__ATOMIC_ACQUIRE, "agent");
        #pragma unroll
        for (int r = 0; r < 8; ++r)
            part += pr[m][r] * ldf(&s_arr[k*SBS + m*64 + g*8 + r]);
    }
    redh[g][l] = part;
    __syncthreads();
    if (g == 0) {
        float tot = 0.0f;
        #pragma unroll
        for (int g2 = 0; g2 < 8; ++g2) tot += redh[g2][l];
        cp[8 * NN + col] = tot;           // 9th accumulator row: near-only, fresh write
    }
}

// ---------- bulk WG: source block k-1 -> targets k+1..15 (inputs all ready) ----------
__device__ void bulk_fn(const float* __restrict__ W, float* wsf,
                        float* ssh, int idx, int k) {
    const int tid = threadIdx.x;
    const int rc = idx & 7, cg = idx >> 3;
    const int row0 = (k-1)*SBS + rc*64;
    const int col = (k+1)*SBS + cg*SBS + tid;
    const float* s_arr = wsf + SARR_OFF;
    float* cp = wsf + CP_OFF;

    if (tid < 64) ssh[tid] = s_arr[row0 + tid];
    __syncthreads();
    const float* wp = W + (size_t)row0 * NN + col;
    float a0 = 0.f, a1 = 0.f, a2 = 0.f, a3 = 0.f;
    #pragma unroll
    for (int i = 0; i < 64; i += 4) {
        a0 += wp[(size_t)(i + 0) * NN] * ssh[i + 0];
        a1 += wp[(size_t)(i + 1) * NN] * ssh[i + 1];
        a2 += wp[(size_t)(i + 2) * NN] * ssh[i + 2];
        a3 += wp[(size_t)(i + 3) * NN] * ssh[i + 3];
    }
    cp[rc * NN + col] += (a0 + a1) + (a2 + a3);   // single writer per (rc,col) per launch
}

__global__ void __launch_bounds__(512, 1) mega_kernel(
    const float* __restrict__ W, const float* __restrict__ b,
    const float* __restrict__ x, float* wsf, int* flags,
    float* __restrict__ out, int k)
{
    __shared__ float sdiag[8 * 4096];   // [m][j][l], pre-scaled by LOG2E, 0 for j>=l
    __shared__ float spub[512];
    __shared__ float sacc[512];
    __shared__ float redN[2][8][64];    // distance-1 fold partials
    __shared__ float redh[8][64];       // helper/near reduction, bulk s staging
    const int bid = blockIdx.x;
    if (bid == 0) {
        solver_fn(W, b, x, wsf, flags, sdiag, spub, sacc, redN, out, k);
        return;
    }
    if ((bid & 7) == 0 && bid <= 48) {          // same XCD as solver (bid%8 heuristic)
        switch (bid >> 3) {
            case 1: helper_fn<2>(W, wsf, flags, redh, k); break;
            case 2: helper_fn<3>(W, wsf, flags, redh, k); break;
            case 3: helper_fn<4>(W, wsf, flags, redh, k); break;
            case 4: helper_fn<5>(W, wsf, flags, redh, k); break;
            case 5: helper_fn<6>(W, wsf, flags, redh, k); break;
            case 6: helper_fn<7>(W, wsf, flags, redh, k); break;
        }
        return;
    }
    if (bid == 56) {                            // prefetcher, same XCD as solver
        if (k < NSB - 1) prefetch_fn(W, k);
        return;
    }
    if (bid < 10) {                             // bids 1..7,9 -> near targets 0..7
        if (k < NSB - 1) near_fn(W, wsf, flags, redh, (bid < 8) ? bid - 1 : 7, k);
        return;
    }
    // bulk: dense index skipping helper/prefetch bids
    if (k >= 1) {
        int nh = (bid >> 3) - 1; if (nh > 6) nh = 6;
        int idx = bid - 10 - nh;
        if (idx < 8 * (15 - k)) bulk_fn(W, wsf, &redh[0][0], idx, k);
    }
}

extern "C" void kernel_launch(void* const* d_in, const int* in_sizes, int n_in,
                              void* d_out, int out_size, void* d_ws, size_t ws_size,
                              hipStream_t stream) {
    const float* x = (const float*)d_in[0];
    const float* W = (const float*)d_in[1];
    const float* b = (const float*)d_in[2];
    float* out = (float*)d_out;
    float* wsf = (float*)d_ws;
    int* wsi   = (int*)d_ws;

    init_ws<<<dim3(288), dim3(256), 0, stream>>>(wsi, wsf);
    for (int k = 0; k < NSB; ++k) {
        int nb;
        if (k == 0)            nb = 57;                 // solver+helpers+near+prefetch
        else if (k == NSB - 1) nb = 49;                 // solver+helpers only
        else if (k <= 9)       nb = 8 * (15 - k) + 16;  // + full bulk set
        else                   nb = 57;                 // bulk fits under bid 57
        mega_kernel<<<dim3(nb), dim3(512), 0, stream>>>(W, b, x, wsf, wsi, out, k);
    }
}